// Round 2
// baseline (1760.489 us; speedup 1.0000x reference)
//
#include <hip/hip_runtime.h>

#define NN 50000
#define NE 600000
#define HIDD 128

static inline int divup(int a, int b) { return (a + b - 1) / b; }

// ---------------- small utility kernels ----------------

__global__ void k_zero_int(int* p, int n) {
    int i = blockIdx.x * blockDim.x + threadIdx.x;
    int stride = gridDim.x * blockDim.x;
    for (; i < n; i += stride) p[i] = 0;
}

// Compute diffusion scalars (sqrt_ab, sqrt_1m), the constant time-embedding
// contribution cvec[128] = (silu(t*tmW1+tmb1) @ tmW2 + tmb2) @ g1_W[256:384,:],
// and zero the L_diff output slot.
__global__ void k_scalars(const int* __restrict__ t_p,
                          const float* __restrict__ tmW1, const float* __restrict__ tmb1,
                          const float* __restrict__ tmW2, const float* __restrict__ tmb2,
                          const float* __restrict__ g1W,
                          float* __restrict__ scal, float* __restrict__ lout) {
    __shared__ float e32[32];
    __shared__ float temb[128];
    const int tid = threadIdx.x;
    const int t = t_p[0];
    if (tid < 32) {
        float x = (float)t * tmW1[tid] + tmb1[tid];
        e32[tid] = x / (1.0f + expf(-x));  // silu
    }
    __syncthreads();
    float acc = tmb2[tid];
    for (int j = 0; j < 32; ++j) acc += e32[j] * tmW2[j * 128 + tid];
    temb[tid] = acc;
    __syncthreads();
    float cv = 0.0f;
    for (int j = 0; j < 128; ++j) cv += temb[j] * g1W[(256 + j) * 128 + tid];
    scal[2 + tid] = cv;
    if (tid == 0) {
        double ab = 1.0;
        for (int i = 0; i <= t; ++i) {
            double beta = 1e-4 + (0.02 - 1e-4) * (double)i / 99.0;
            ab *= (1.0 - beta);
        }
        scal[0] = (float)sqrt(ab);
        scal[1] = (float)sqrt(1.0 - ab);
        lout[0] = 0.0f;
    }
}

__global__ void k_hist(const int* __restrict__ dst, int* __restrict__ cnt, int e) {
    int i = blockIdx.x * blockDim.x + threadIdx.x;
    if (i < e) atomicAdd(&cnt[dst[i]], 1);
}

#define SCAN_B 256
__global__ void k_scan1(const int* __restrict__ cnt, int* __restrict__ exc,
                        int* __restrict__ bsum, int n) {
    __shared__ int s[SCAN_B];
    int i = blockIdx.x * SCAN_B + threadIdx.x;
    int v = (i < n) ? cnt[i] : 0;
    s[threadIdx.x] = v;
    __syncthreads();
    for (int off = 1; off < SCAN_B; off <<= 1) {
        int tv = (threadIdx.x >= off) ? s[threadIdx.x - off] : 0;
        __syncthreads();
        s[threadIdx.x] += tv;
        __syncthreads();
    }
    if (i < n) exc[i] = s[threadIdx.x] - v;
    if (threadIdx.x == SCAN_B - 1) bsum[blockIdx.x] = s[SCAN_B - 1];
}

__global__ void k_scan2(int* __restrict__ bsum, int nb) {
    __shared__ int s[SCAN_B];
    int v = (threadIdx.x < nb) ? bsum[threadIdx.x] : 0;
    s[threadIdx.x] = v;
    __syncthreads();
    for (int off = 1; off < SCAN_B; off <<= 1) {
        int tv = (threadIdx.x >= off) ? s[threadIdx.x - off] : 0;
        __syncthreads();
        s[threadIdx.x] += tv;
        __syncthreads();
    }
    if (threadIdx.x < nb) bsum[threadIdx.x] = s[threadIdx.x] - v;
}

__global__ void k_scan3(int* __restrict__ exc, const int* __restrict__ bsum, int n, int total) {
    int i = blockIdx.x * SCAN_B + threadIdx.x;
    if (i < n) exc[i] += bsum[blockIdx.x];
    if (i == 0) exc[n] = total;
}

__global__ void k_fill(const int* __restrict__ src, const int* __restrict__ dst,
                       const int* __restrict__ rowptr, int* __restrict__ fill,
                       int* __restrict__ colA, int e) {
    int i = blockIdx.x * blockDim.x + threadIdx.x;
    if (i < e) {
        int d = dst[i];
        int p = atomicAdd(&fill[d], 1);
        colA[rowptr[d] + p] = src[i];
    }
}

__global__ void k_dinv(const int* __restrict__ cnt, float* __restrict__ dinv, int n) {
    int i = blockIdx.x * blockDim.x + threadIdx.x;
    if (i < n) dinv[i] = rsqrtf((float)cnt[i] + 1.0f);  // +1 = self loop
}

// ---------------- GEMM: out = A@Wa (+ B@Wb) (+ cvec), K=128 per operand, 128 cols ----------------
__global__ __launch_bounds__(256) void k_gemm(
    const float* __restrict__ A, const float* __restrict__ Wa,
    const float* __restrict__ B, const float* __restrict__ Wb,
    const float* __restrict__ cvec, float* __restrict__ out, int nrows) {
    __shared__ float sW[64 * 128];  // 32KB: K-chunk of W
    __shared__ float sA[64 * 64];   // 16KB: 64-row x 64-K chunk of A
    const int tid = threadIdx.x;
    const int tc = tid & 31;   // col group: cols 4*tc .. 4*tc+3
    const int tr = tid >> 5;   // row group: rows tr*8 .. tr*8+7
    const int r0 = blockIdx.x * 64;

    float acc[8][4];
#pragma unroll
    for (int i = 0; i < 8; ++i)
#pragma unroll
        for (int c = 0; c < 4; ++c) acc[i][c] = 0.0f;

    const int npass = (B != nullptr) ? 2 : 1;
    for (int pass = 0; pass < npass; ++pass) {
        const float* Ax = pass ? B : A;
        const float* Wx = pass ? Wb : Wa;
        for (int kh = 0; kh < 2; ++kh) {
            // stage W chunk: rows kh*64..+64, 128 cols
#pragma unroll
            for (int j = 0; j < 8; ++j) {
                int fid = tid + j * 256;  // float4 id, 0..2047
                int row = fid >> 5;
                int c4 = fid & 31;
                *(float4*)&sW[row * 128 + c4 * 4] =
                    *(const float4*)&Wx[(kh * 64 + row) * 128 + c4 * 4];
            }
            // stage A chunk: 64 rows x 64 K
#pragma unroll
            for (int j = 0; j < 4; ++j) {
                int fid = tid + j * 256;  // 0..1023
                int row = fid >> 4;
                int c4 = fid & 15;
                int gr = r0 + row;
                float4 v = make_float4(0.f, 0.f, 0.f, 0.f);
                if (gr < nrows) v = *(const float4*)&Ax[(size_t)gr * 128 + kh * 64 + c4 * 4];
                *(float4*)&sA[row * 64 + c4 * 4] = v;
            }
            __syncthreads();
#pragma unroll
            for (int kk = 0; kk < 64; kk += 4) {
                float4 w0 = *(float4*)&sW[(kk + 0) * 128 + tc * 4];
                float4 w1 = *(float4*)&sW[(kk + 1) * 128 + tc * 4];
                float4 w2 = *(float4*)&sW[(kk + 2) * 128 + tc * 4];
                float4 w3 = *(float4*)&sW[(kk + 3) * 128 + tc * 4];
#pragma unroll
                for (int i = 0; i < 8; ++i) {
                    float4 a = *(float4*)&sA[(tr * 8 + i) * 64 + kk];
                    acc[i][0] += a.x * w0.x + a.y * w1.x + a.z * w2.x + a.w * w3.x;
                    acc[i][1] += a.x * w0.y + a.y * w1.y + a.z * w2.y + a.w * w3.y;
                    acc[i][2] += a.x * w0.z + a.y * w1.z + a.z * w2.z + a.w * w3.z;
                    acc[i][3] += a.x * w0.w + a.y * w1.w + a.z * w2.w + a.w * w3.w;
                }
            }
            __syncthreads();
        }
    }
    float4 cv = make_float4(0.f, 0.f, 0.f, 0.f);
    if (cvec) cv = *(const float4*)&cvec[tc * 4];
#pragma unroll
    for (int i = 0; i < 8; ++i) {
        int r = r0 + tr * 8 + i;
        if (r < nrows) {
            float4 o;
            o.x = acc[i][0] + cv.x;
            o.y = acc[i][1] + cv.y;
            o.z = acc[i][2] + cv.z;
            o.w = acc[i][3] + cv.w;
            *(float4*)&out[(size_t)r * 128 + tc * 4] = o;
        }
    }
}

// ---------------- GCN aggregation: out[d] = dinv[d]*(sum_e dinv[s]*h[s] + dinv[d]*h[d]) + b ----------------
__global__ __launch_bounds__(256) void k_agg(
    const float* __restrict__ h, const int* __restrict__ rowptr,
    const int* __restrict__ colA, const float* __restrict__ dinv,
    const float* __restrict__ bias, float* __restrict__ out, int n, int do_relu) {
    const int w = (blockIdx.x * blockDim.x + threadIdx.x) >> 6;  // one wave per row
    const int lane = threadIdx.x & 63;
    if (w >= n) return;
    const float di = dinv[w];
    float2 acc;
    {
        float2 hs = ((const float2*)&h[(size_t)w * 128])[lane];
        acc.x = di * hs.x;
        acc.y = di * hs.y;
    }
    const int e0 = rowptr[w];
    const int e1 = rowptr[w + 1];
    for (int e = e0; e < e1; ++e) {
        int s = colA[e];
        float ws = dinv[s];
        float2 hv = ((const float2*)&h[(size_t)s * 128])[lane];
        acc.x += ws * hv.x;
        acc.y += ws * hv.y;
    }
    float2 b2 = ((const float2*)bias)[lane];
    float ox = di * acc.x + b2.x;
    float oy = di * acc.y + b2.y;
    if (do_relu) {
        ox = fmaxf(ox, 0.0f);
        oy = fmaxf(oy, 0.0f);
    }
    ((float2*)&out[(size_t)w * 128])[lane] = make_float2(ox, oy);
}

// ---------------- h_diff output + h_t formation (in place) ----------------
__global__ void k_mix(float* __restrict__ V1, float* __restrict__ V2,
                      const float* __restrict__ n1, const float* __restrict__ n2,
                      const float* __restrict__ scal, float* __restrict__ hdiff, int total4) {
    const float sa = scal[0];
    const float sm = scal[1];
    int i = blockIdx.x * blockDim.x + threadIdx.x;
    const int stride = gridDim.x * blockDim.x;
    for (; i < total4; i += stride) {
        float4 a = ((const float4*)V1)[i];
        float4 b = ((const float4*)V2)[i];
        float4 x = ((const float4*)n1)[i];
        float4 y = ((const float4*)n2)[i];
        float4 hd;
        hd.x = 0.5f * (a.x + b.x);
        hd.y = 0.5f * (a.y + b.y);
        hd.z = 0.5f * (a.z + b.z);
        hd.w = 0.5f * (a.w + b.w);
        ((float4*)hdiff)[i] = hd;
        float4 o1, o2;
        o1.x = sa * a.x + sm * x.x; o1.y = sa * a.y + sm * x.y;
        o1.z = sa * a.z + sm * x.z; o1.w = sa * a.w + sm * x.w;
        o2.x = sa * b.x + sm * y.x; o2.y = sa * b.y + sm * y.y;
        o2.z = sa * b.z + sm * y.z; o2.w = sa * b.w + sm * y.w;
        ((float4*)V1)[i] = o1;
        ((float4*)V2)[i] = o2;
    }
}

// ---------------- L_diff = (sum (p1-n1)^2 + sum (p2-n2)^2) / (N*128) ----------------
__global__ void k_loss(const float* __restrict__ V1, const float* __restrict__ V2,
                       const float* __restrict__ n1, const float* __restrict__ n2,
                       float* __restrict__ outs, int total4, float inv_total) {
    float s = 0.0f;
    int i = blockIdx.x * blockDim.x + threadIdx.x;
    const int stride = gridDim.x * blockDim.x;
    for (; i < total4; i += stride) {
        float4 a = ((const float4*)V1)[i];
        float4 x = ((const float4*)n1)[i];
        float4 b = ((const float4*)V2)[i];
        float4 y = ((const float4*)n2)[i];
        float dx;
        dx = a.x - x.x; s += dx * dx;
        dx = a.y - x.y; s += dx * dx;
        dx = a.z - x.z; s += dx * dx;
        dx = a.w - x.w; s += dx * dx;
        dx = b.x - y.x; s += dx * dx;
        dx = b.y - y.y; s += dx * dx;
        dx = b.z - y.z; s += dx * dx;
        dx = b.w - y.w; s += dx * dx;
    }
    __shared__ float red[4];
    for (int off = 32; off > 0; off >>= 1) s += __shfl_down(s, off, 64);
    const int lane = threadIdx.x & 63;
    const int wid = threadIdx.x >> 6;
    if (lane == 0) red[wid] = s;
    __syncthreads();
    if (threadIdx.x == 0) {
        float t = red[0] + red[1] + red[2] + red[3];
        atomicAdd(outs, t * inv_total);
    }
}

// ---------------- host ----------------
extern "C" void kernel_launch(void* const* d_in, const int* in_sizes, int n_in,
                              void* d_out, int out_size, void* d_ws, size_t ws_size,
                              hipStream_t stream) {
    const float* X      = (const float*)d_in[0];
    const int*   ei1    = (const int*)d_in[1];
    const int*   ei2    = (const int*)d_in[2];
    const int*   t_p    = (const int*)d_in[3];
    const float* noise1 = (const float*)d_in[4];
    const float* noise2 = (const float*)d_in[5];
    const float* encW1  = (const float*)d_in[6];
    const float* encb1  = (const float*)d_in[7];
    const float* encW2  = (const float*)d_in[8];
    const float* encb2  = (const float*)d_in[9];
    const float* tmW1   = (const float*)d_in[10];
    const float* tmb1   = (const float*)d_in[11];
    const float* tmW2   = (const float*)d_in[12];
    const float* tmb2   = (const float*)d_in[13];
    const float* g1W    = (const float*)d_in[14];
    const float* g1b    = (const float*)d_in[15];
    const float* g2W    = (const float*)d_in[16];
    const float* g2b    = (const float*)d_in[17];
    const float* g3W    = (const float*)d_in[18];
    const float* g3b    = (const float*)d_in[19];

    float* out_hdiff = (float*)d_out;
    float* out_L     = (float*)d_out + (size_t)NN * 128;

    // workspace carve-up (256B aligned)
    char* p = (char*)d_ws;
    auto alloc = [&](size_t bytes) -> void* {
        void* r = (void*)p;
        p += (bytes + 255) & ~(size_t)255;
        return r;
    };
    int* cnts   = (int*)alloc((size_t)4 * NN * sizeof(int));  // cnt1,cnt2,fill1,fill2
    int* cnt1 = cnts, *cnt2 = cnts + NN, *fill1 = cnts + 2 * NN, *fill2 = cnts + 3 * NN;
    int* rowptr1 = (int*)alloc((NN + 1) * sizeof(int));
    int* rowptr2 = (int*)alloc((NN + 1) * sizeof(int));
    int* bsum    = (int*)alloc(256 * sizeof(int));
    int* col1    = (int*)alloc((size_t)NE * sizeof(int));
    int* col2    = (int*)alloc((size_t)NE * sizeof(int));
    float* dinv1 = (float*)alloc(NN * sizeof(float));
    float* dinv2 = (float*)alloc(NN * sizeof(float));
    float* scal  = (float*)alloc(256 * sizeof(float));  // [0]=sa [1]=sm [2..129]=cvec
    float* T0 = (float*)alloc((size_t)NN * 128 * sizeof(float));
    float* T1 = (float*)alloc((size_t)NN * 128 * sizeof(float));
    float* V1 = (float*)alloc((size_t)NN * 128 * sizeof(float));
    float* V2 = (float*)alloc((size_t)NN * 128 * sizeof(float));

    const int* src1 = ei1;
    const int* dst1 = ei1 + NE;
    const int* src2 = ei2;
    const int* dst2 = ei2 + NE;

    const int nbN   = divup(NN, 256);        // 196
    const int nbE   = divup(NE, 256);        // 2344
    const int nb4N  = divup(4 * NN, 256);
    const int nbG   = divup(NN, 64);         // gemm blocks: 782
    const int nbAgg = divup(NN, 4);          // 4 rows(waves)/block: 12500
    const int total4 = NN * 128 / 4;

    // --- graph preprocessing ---
    k_zero_int<<<nb4N, 256, 0, stream>>>(cnts, 4 * NN);
    k_scalars<<<1, 128, 0, stream>>>(t_p, tmW1, tmb1, tmW2, tmb2, g1W, scal, out_L);
    k_hist<<<nbE, 256, 0, stream>>>(dst1, cnt1, NE);
    k_hist<<<nbE, 256, 0, stream>>>(dst2, cnt2, NE);
    k_scan1<<<nbN, 256, 0, stream>>>(cnt1, rowptr1, bsum, NN);
    k_scan2<<<1, 256, 0, stream>>>(bsum, nbN);
    k_scan3<<<nbN, 256, 0, stream>>>(rowptr1, bsum, NN, NE);
    k_scan1<<<nbN, 256, 0, stream>>>(cnt2, rowptr2, bsum, NN);
    k_scan2<<<1, 256, 0, stream>>>(bsum, nbN);
    k_scan3<<<nbN, 256, 0, stream>>>(rowptr2, bsum, NN, NE);
    k_dinv<<<nbN, 256, 0, stream>>>(cnt1, dinv1, NN);
    k_dinv<<<nbN, 256, 0, stream>>>(cnt2, dinv2, NN);
    k_fill<<<nbE, 256, 0, stream>>>(src1, dst1, rowptr1, fill1, col1, NE);
    k_fill<<<nbE, 256, 0, stream>>>(src2, dst2, rowptr2, fill2, col2, NE);

    // --- encoder ---
    // shared first GEMM: T0 = X @ enc_W1
    k_gemm<<<nbG, 256, 0, stream>>>(X, encW1, nullptr, nullptr, nullptr, T0, NN);
    k_agg<<<nbAgg, 256, 0, stream>>>(T0, rowptr1, col1, dinv1, encb1, V1, NN, 1);
    k_agg<<<nbAgg, 256, 0, stream>>>(T0, rowptr2, col2, dinv2, encb1, V2, NN, 1);
    k_gemm<<<nbG, 256, 0, stream>>>(V1, encW2, nullptr, nullptr, nullptr, T0, NN);
    k_agg<<<nbAgg, 256, 0, stream>>>(T0, rowptr1, col1, dinv1, encb2, V1, NN, 0);  // h0_v1
    k_gemm<<<nbG, 256, 0, stream>>>(V2, encW2, nullptr, nullptr, nullptr, T0, NN);
    k_agg<<<nbAgg, 256, 0, stream>>>(T0, rowptr2, col2, dinv2, encb2, V2, NN, 0);  // h0_v2

    // --- h_diff output, h_t in place ---
    k_mix<<<2048, 256, 0, stream>>>(V1, V2, noise1, noise2, scal, out_hdiff, total4);

    // --- denoiser layer 1 (concat folded: self@Wa + other@Wb + cvec) ---
    const float* g1Wa = g1W;
    const float* g1Wb = g1W + 128 * 128;
    k_gemm<<<nbG, 256, 0, stream>>>(V1, g1Wa, V2, g1Wb, scal + 2, T0, NN);
    k_gemm<<<nbG, 256, 0, stream>>>(V2, g1Wa, V1, g1Wb, scal + 2, T1, NN);
    k_agg<<<nbAgg, 256, 0, stream>>>(T0, rowptr1, col1, dinv1, g1b, V1, NN, 1);
    k_agg<<<nbAgg, 256, 0, stream>>>(T1, rowptr2, col2, dinv2, g1b, V2, NN, 1);

    // --- denoiser layer 2 ---
    k_gemm<<<nbG, 256, 0, stream>>>(V1, g2W, nullptr, nullptr, nullptr, T0, NN);
    k_agg<<<nbAgg, 256, 0, stream>>>(T0, rowptr1, col1, dinv1, g2b, V1, NN, 1);
    k_gemm<<<nbG, 256, 0, stream>>>(V2, g2W, nullptr, nullptr, nullptr, T0, NN);
    k_agg<<<nbAgg, 256, 0, stream>>>(T0, rowptr2, col2, dinv2, g2b, V2, NN, 1);

    // --- denoiser layer 3 (no relu) ---
    k_gemm<<<nbG, 256, 0, stream>>>(V1, g3W, nullptr, nullptr, nullptr, T0, NN);
    k_agg<<<nbAgg, 256, 0, stream>>>(T0, rowptr1, col1, dinv1, g3b, V1, NN, 0);  // pred_v1
    k_gemm<<<nbG, 256, 0, stream>>>(V2, g3W, nullptr, nullptr, nullptr, T0, NN);
    k_agg<<<nbAgg, 256, 0, stream>>>(T0, rowptr2, col2, dinv2, g3b, V2, NN, 0);  // pred_v2

    // --- loss ---
    k_loss<<<2048, 256, 0, stream>>>(V1, V2, noise1, noise2, out_L, total4,
                                     1.0f / (float)((size_t)NN * 128));
}

// Round 4
// 941.194 us; speedup vs baseline: 1.8705x; 1.8705x over previous
//
#include <hip/hip_runtime.h>

#define NN 50000
#define NE 600000

typedef __attribute__((ext_vector_type(8))) short short8;
typedef __attribute__((ext_vector_type(4))) float f32x4;

static inline int divup(int a, int b) { return (a + b - 1) / b; }

__device__ inline unsigned short f2bf(float f) {
    unsigned int u = __float_as_uint(f);
    unsigned int r = (u + 0x7FFFu + ((u >> 16) & 1u)) >> 16;
    return (unsigned short)r;
}
__device__ inline float bflo(unsigned int u) { return __uint_as_float(u << 16); }
__device__ inline float bfhi(unsigned int u) { return __uint_as_float(u & 0xFFFF0000u); }

// ---------------- small utility kernels ----------------

__global__ void k_zero_int(int* p, int n) {
    int i = blockIdx.x * blockDim.x + threadIdx.x;
    int stride = gridDim.x * blockDim.x;
    for (; i < n; i += stride) p[i] = 0;
}

// scalars: sqrt_ab, sqrt_1m, cvec[128] = temb @ g1_W[256:384,:], zero L out
__global__ void k_scalars(const int* __restrict__ t_p,
                          const float* __restrict__ tmW1, const float* __restrict__ tmb1,
                          const float* __restrict__ tmW2, const float* __restrict__ tmb2,
                          const float* __restrict__ g1W,
                          float* __restrict__ scal, float* __restrict__ lout) {
    __shared__ float e32[32];
    __shared__ float temb[128];
    const int tid = threadIdx.x;
    const int t = t_p[0];
    if (tid < 32) {
        float x = (float)t * tmW1[tid] + tmb1[tid];
        e32[tid] = x / (1.0f + expf(-x));  // silu
    }
    __syncthreads();
    float acc = tmb2[tid];
    for (int j = 0; j < 32; ++j) acc += e32[j] * tmW2[j * 128 + tid];
    temb[tid] = acc;
    __syncthreads();
    float cv = 0.0f;
    for (int j = 0; j < 128; ++j) cv += temb[j] * g1W[(256 + j) * 128 + tid];
    scal[2 + tid] = cv;
    if (tid == 0) {
        double ab = 1.0;
        for (int i = 0; i <= t; ++i) {
            double beta = 1e-4 + (0.02 - 1e-4) * (double)i / 99.0;
            ab *= (1.0 - beta);
        }
        scal[0] = (float)sqrt(ab);
        scal[1] = (float)sqrt(1.0 - ab);
        lout[0] = 0.0f;
    }
}

// Weight prep: 6 matrices of 128x128 f32 (row-major [k][n]) -> bf16 W^T, XOR-swizzled:
// element (n,k) stored at byte ((n<<8)|(k<<1)) ^ ((n&7)<<4) within each 32KB image.
// m: 0=encW1 1=encW2 2=g1Wa 3=g1Wb 4=g2W 5=g3W
__global__ void k_wprep(const float* __restrict__ encW1, const float* __restrict__ encW2,
                        const float* __restrict__ g1W, const float* __restrict__ g2W,
                        const float* __restrict__ g3W, unsigned short* __restrict__ WtS) {
    int i = blockIdx.x * blockDim.x + threadIdx.x;  // 0 .. 6*16384
    if (i >= 6 * 16384) return;
    int m = i >> 14;
    int r = i & 16383;
    int k = r >> 7;
    int n = r & 127;
    const float* src;
    switch (m) {
        case 0: src = encW1; break;
        case 1: src = encW2; break;
        case 2: src = g1W; break;
        case 3: src = g1W + 16384; break;
        case 4: src = g2W; break;
        default: src = g3W; break;
    }
    unsigned short v = f2bf(src[k * 128 + n]);
    unsigned int byte = (((unsigned)n << 8) | ((unsigned)k << 1)) ^ (((unsigned)n & 7u) << 4);
    WtS[(m << 14) + (byte >> 1)] = v;
}

// f32 -> bf16 cast (4 elems/thread)
__global__ void k_xcast(const float* __restrict__ in, unsigned short* __restrict__ out, int n4) {
    int i = blockIdx.x * blockDim.x + threadIdx.x;
    int stride = gridDim.x * blockDim.x;
    for (; i < n4; i += stride) {
        float4 v = ((const float4*)in)[i];
        ushort4 o;
        o.x = f2bf(v.x); o.y = f2bf(v.y); o.z = f2bf(v.z); o.w = f2bf(v.w);
        ((ushort4*)out)[i] = o;
    }
}

__global__ void k_hist(const int* __restrict__ dst, int* __restrict__ cnt, int e) {
    int i = blockIdx.x * blockDim.x + threadIdx.x;
    if (i < e) atomicAdd(&cnt[dst[i]], 1);
}

#define SCAN_B 256
__global__ void k_scan1(const int* __restrict__ cnt, int* __restrict__ exc,
                        int* __restrict__ bsum, int n) {
    __shared__ int s[SCAN_B];
    int i = blockIdx.x * SCAN_B + threadIdx.x;
    int v = (i < n) ? cnt[i] : 0;
    s[threadIdx.x] = v;
    __syncthreads();
    for (int off = 1; off < SCAN_B; off <<= 1) {
        int tv = (threadIdx.x >= off) ? s[threadIdx.x - off] : 0;
        __syncthreads();
        s[threadIdx.x] += tv;
        __syncthreads();
    }
    if (i < n) exc[i] = s[threadIdx.x] - v;
    if (threadIdx.x == SCAN_B - 1) bsum[blockIdx.x] = s[SCAN_B - 1];
}

__global__ void k_scan2(int* __restrict__ bsum, int nb) {
    __shared__ int s[SCAN_B];
    int v = (threadIdx.x < nb) ? bsum[threadIdx.x] : 0;
    s[threadIdx.x] = v;
    __syncthreads();
    for (int off = 1; off < SCAN_B; off <<= 1) {
        int tv = (threadIdx.x >= off) ? s[threadIdx.x - off] : 0;
        __syncthreads();
        s[threadIdx.x] += tv;
        __syncthreads();
    }
    if (threadIdx.x < nb) bsum[threadIdx.x] = s[threadIdx.x] - v;
}

__global__ void k_scan3(int* __restrict__ exc, const int* __restrict__ bsum, int n, int total) {
    int i = blockIdx.x * SCAN_B + threadIdx.x;
    if (i < n) exc[i] += bsum[blockIdx.x];
    if (i == 0) exc[n] = total;
}

__global__ void k_fill(const int* __restrict__ src, const int* __restrict__ dst,
                       const int* __restrict__ rowptr, int* __restrict__ fill,
                       int* __restrict__ colA, int e) {
    int i = blockIdx.x * blockDim.x + threadIdx.x;
    if (i < e) {
        int d = dst[i];
        int p = atomicAdd(&fill[d], 1);
        colA[rowptr[d] + p] = src[i];
    }
}

__global__ void k_dinv(const int* __restrict__ cnt, float* __restrict__ dinv, int n) {
    int i = blockIdx.x * blockDim.x + threadIdx.x;
    if (i < n) dinv[i] = rsqrtf((float)cnt[i] + 1.0f);  // +1 = self loop
}

// ---------------- MFMA GEMM: out(bf16) = A@Wa (+ B@Wb) (+ cvec) ----------------
// A,B: bf16 [nrows][128] row-major. Wa,Wb: pre-swizzled bf16 W^T 32KB images.
// Block: 64 rows, 4 waves; wave = 16 rows x 128 cols; 16x16x32 MFMA.
__global__ __launch_bounds__(256) void k_mgemm(
    const unsigned short* __restrict__ A, const unsigned short* __restrict__ Wa,
    const unsigned short* __restrict__ B, const unsigned short* __restrict__ Wb,
    const float* __restrict__ cvec, unsigned short* __restrict__ out, int nrows) {
    __shared__ unsigned short sW[16384];  // 32KB swizzled W^T
    const int tid = threadIdx.x;
    const int wv = tid >> 6;
    const int l = tid & 63;
    const int lrow = l & 15;   // A-row / C-col within tile
    const int lk = l >> 4;     // 0..3: K-subgroup / C-row-group
    const int r0 = blockIdx.x * 64 + wv * 16;

    f32x4 acc[8];
#pragma unroll
    for (int ct = 0; ct < 8; ++ct) acc[ct] = (f32x4){0.f, 0.f, 0.f, 0.f};

    const unsigned short* Aptr[2] = {A, B};
    const unsigned short* Wptr[2] = {Wa, Wb};
    const int np = (B != nullptr) ? 2 : 1;

    int arow = r0 + lrow;
    if (arow >= nrows) arow = nrows - 1;

    for (int p = 0; p < np; ++p) {
        __syncthreads();  // protect sW from previous pass readers
        {
            const uint4* s = (const uint4*)Wptr[p];
            uint4* d = (uint4*)sW;
#pragma unroll
            for (int j = 0; j < 8; ++j) d[tid + j * 256] = s[tid + j * 256];
        }
        __syncthreads();
        const unsigned short* abase = Aptr[p] + (size_t)arow * 128 + lk * 8;
#pragma unroll
        for (int ks = 0; ks < 4; ++ks) {
            short8 af = *(const short8*)(abase + ks * 32);
            const int kb2 = (lk * 8 + ks * 32) << 1;  // byte offset of k-base
#pragma unroll
            for (int ct = 0; ct < 8; ++ct) {
                int n = ct * 16 + lrow;
                int byteoff = ((n << 8) + kb2) ^ ((l & 7) << 4);
                short8 bf = *(const short8*)((const char*)sW + byteoff);
                acc[ct] = __builtin_amdgcn_mfma_f32_16x16x32_bf16(af, bf, acc[ct], 0, 0, 0);
            }
        }
    }
    // epilogue: C[row = r0 + lk*4 + reg][col = ct*16 + lrow]
#pragma unroll
    for (int ct = 0; ct < 8; ++ct) {
        float cv = cvec ? cvec[ct * 16 + lrow] : 0.0f;
#pragma unroll
        for (int rg = 0; rg < 4; ++rg) {
            int row = r0 + lk * 4 + rg;
            if (row < nrows) out[(size_t)row * 128 + ct * 16 + lrow] = f2bf(acc[ct][rg] + cv);
        }
    }
}

// ---------------- GCN aggregation (bf16 in, bf16 out) ----------------
// out[d] = relu?( dinv[d]*(dinv[d]*h[d] + sum_s dinv[s]*h[s]) + b )
__global__ __launch_bounds__(256) void k_agg(
    const unsigned short* __restrict__ h, const int* __restrict__ rowptr,
    const int* __restrict__ colA, const float* __restrict__ dinv,
    const float* __restrict__ bias, unsigned short* __restrict__ out, int n, int do_relu) {
    const int d = (blockIdx.x * blockDim.x + threadIdx.x) >> 6;
    const int l = threadIdx.x & 63;
    if (d >= n) return;
    const float di = dinv[d];
    unsigned int su = ((const unsigned int*)h)[(size_t)d * 64 + l];
    float ax = di * bflo(su);
    float ay = di * bfhi(su);
    const int e0 = rowptr[d];
    const int e1 = rowptr[d + 1];
    for (int base = e0; base < e1; base += 64) {
        int cnt = min(64, e1 - base);
        int cs = 0;
        float ws = 0.0f;
        if (base + l < e1) {
            cs = colA[base + l];
            ws = dinv[cs];
        }
        for (int j = 0; j < cnt; ++j) {
            int s = __shfl(cs, j);
            float w = __shfl(ws, j);
            unsigned int u = ((const unsigned int*)h)[(size_t)s * 64 + l];
            ax += w * bflo(u);
            ay += w * bfhi(u);
        }
    }
    float2 b2 = ((const float2*)bias)[l];
    float ox = di * ax + b2.x;
    float oy = di * ay + b2.y;
    if (do_relu) {
        ox = fmaxf(ox, 0.0f);
        oy = fmaxf(oy, 0.0f);
    }
    ((unsigned int*)out)[(size_t)d * 64 + l] =
        (unsigned int)f2bf(ox) | ((unsigned int)f2bf(oy) << 16);
}

// ---------------- h_diff (f32 out) + h_t (bf16) ----------------
__global__ void k_mix(const unsigned short* __restrict__ F1, const unsigned short* __restrict__ F2,
                      const float* __restrict__ n1, const float* __restrict__ n2,
                      const float* __restrict__ scal, float* __restrict__ hdiff,
                      unsigned short* __restrict__ B1, unsigned short* __restrict__ B2, int total2) {
    const float sa = scal[0];
    const float sm = scal[1];
    int i = blockIdx.x * blockDim.x + threadIdx.x;
    const int stride = gridDim.x * blockDim.x;
    for (; i < total2; i += stride) {
        unsigned int u1 = ((const unsigned int*)F1)[i];
        unsigned int u2 = ((const unsigned int*)F2)[i];
        float a0 = bflo(u1), a1 = bfhi(u1);
        float b0 = bflo(u2), b1 = bfhi(u2);
        float2 x = ((const float2*)n1)[i];
        float2 y = ((const float2*)n2)[i];
        float2 hd;
        hd.x = 0.5f * (a0 + b0);
        hd.y = 0.5f * (a1 + b1);
        ((float2*)hdiff)[i] = hd;
        float h1x = sa * a0 + sm * x.x, h1y = sa * a1 + sm * x.y;
        float h2x = sa * b0 + sm * y.x, h2y = sa * b1 + sm * y.y;
        ((unsigned int*)B1)[i] = (unsigned int)f2bf(h1x) | ((unsigned int)f2bf(h1y) << 16);
        ((unsigned int*)B2)[i] = (unsigned int)f2bf(h2x) | ((unsigned int)f2bf(h2y) << 16);
    }
}

// ---------------- L_diff ----------------
__global__ void k_loss(const unsigned short* __restrict__ P1, const unsigned short* __restrict__ P2,
                       const float* __restrict__ n1, const float* __restrict__ n2,
                       float* __restrict__ outs, int total2, float inv_total) {
    float s = 0.0f;
    int i = blockIdx.x * blockDim.x + threadIdx.x;
    const int stride = gridDim.x * blockDim.x;
    for (; i < total2; i += stride) {
        unsigned int u1 = ((const unsigned int*)P1)[i];
        unsigned int u2 = ((const unsigned int*)P2)[i];
        float2 x = ((const float2*)n1)[i];
        float2 y = ((const float2*)n2)[i];
        float d0 = bflo(u1) - x.x, d1 = bfhi(u1) - x.y;
        float d2 = bflo(u2) - y.x, d3 = bfhi(u2) - y.y;
        s += d0 * d0 + d1 * d1 + d2 * d2 + d3 * d3;
    }
    __shared__ float red[4];
    for (int off = 32; off > 0; off >>= 1) s += __shfl_down(s, off, 64);
    const int lane = threadIdx.x & 63;
    const int wid = threadIdx.x >> 6;
    if (lane == 0) red[wid] = s;
    __syncthreads();
    if (threadIdx.x == 0) {
        float t = red[0] + red[1] + red[2] + red[3];
        atomicAdd(outs, t * inv_total);
    }
}

// ---------------- host ----------------
extern "C" void kernel_launch(void* const* d_in, const int* in_sizes, int n_in,
                              void* d_out, int out_size, void* d_ws, size_t ws_size,
                              hipStream_t stream) {
    const float* X      = (const float*)d_in[0];
    const int*   ei1    = (const int*)d_in[1];
    const int*   ei2    = (const int*)d_in[2];
    const int*   t_p    = (const int*)d_in[3];
    const float* noise1 = (const float*)d_in[4];
    const float* noise2 = (const float*)d_in[5];
    const float* encW1  = (const float*)d_in[6];
    const float* encb1  = (const float*)d_in[7];
    const float* encW2  = (const float*)d_in[8];
    const float* encb2  = (const float*)d_in[9];
    const float* tmW1   = (const float*)d_in[10];
    const float* tmb1   = (const float*)d_in[11];
    const float* tmW2   = (const float*)d_in[12];
    const float* tmb2   = (const float*)d_in[13];
    const float* g1W    = (const float*)d_in[14];
    const float* g1b    = (const float*)d_in[15];
    const float* g2W    = (const float*)d_in[16];
    const float* g2b    = (const float*)d_in[17];
    const float* g3W    = (const float*)d_in[18];
    const float* g3b    = (const float*)d_in[19];

    float* out_hdiff = (float*)d_out;
    float* out_L     = (float*)d_out + (size_t)NN * 128;

    char* p = (char*)d_ws;
    auto alloc = [&](size_t bytes) -> void* {
        void* r = (void*)p;
        p += (bytes + 255) & ~(size_t)255;
        return r;
    };
    int* cnts = (int*)alloc((size_t)4 * NN * sizeof(int));
    int *cnt1 = cnts, *cnt2 = cnts + NN, *fill1 = cnts + 2 * NN, *fill2 = cnts + 3 * NN;
    int* rowptr1 = (int*)alloc((NN + 1) * sizeof(int));
    int* rowptr2 = (int*)alloc((NN + 1) * sizeof(int));
    int* bsum    = (int*)alloc(256 * sizeof(int));
    int* col1    = (int*)alloc((size_t)NE * sizeof(int));
    int* col2    = (int*)alloc((size_t)NE * sizeof(int));
    float* dinv1 = (float*)alloc(NN * sizeof(float));
    float* dinv2 = (float*)alloc(NN * sizeof(float));
    float* scal  = (float*)alloc(256 * sizeof(float));  // [0]=sa [1]=sm [2..129]=cvec
    unsigned short* WtS = (unsigned short*)alloc((size_t)6 * 16384 * sizeof(unsigned short));
    const size_t FB = (size_t)NN * 128;
    unsigned short* Xb = (unsigned short*)alloc(FB * 2);  // also V1d (denoiser v1 act)
    unsigned short* A1 = (unsigned short*)alloc(FB * 2);  // enc act v1, then B1 (h_t_v1)
    unsigned short* A2 = (unsigned short*)alloc(FB * 2);  // enc act v2, then B2 (h_t_v2)
    unsigned short* D0 = (unsigned short*)alloc(FB * 2);  // GEMM->agg scratch
    unsigned short* F1 = (unsigned short*)alloc(FB * 2);  // h0_v1, then pred_v1
    unsigned short* F2 = (unsigned short*)alloc(FB * 2);  // h0_v2, then V2d, then pred_v2
    unsigned short* V1d = Xb;
    unsigned short* V2d = F2;

    const unsigned short* W_enc1 = WtS;
    const unsigned short* W_enc2 = WtS + 1 * 16384;
    const unsigned short* W_g1a  = WtS + 2 * 16384;
    const unsigned short* W_g1b  = WtS + 3 * 16384;
    const unsigned short* W_g2   = WtS + 4 * 16384;
    const unsigned short* W_g3   = WtS + 5 * 16384;

    const int* src1 = ei1;
    const int* dst1 = ei1 + NE;
    const int* src2 = ei2;
    const int* dst2 = ei2 + NE;

    const int nbN   = divup(NN, 256);
    const int nbE   = divup(NE, 256);
    const int nb4N  = divup(4 * NN, 256);
    const int nbG   = divup(NN, 64);   // 782
    const int nbAgg = divup(NN, 4);    // 12500
    const int total2 = NN * 64;        // uint-pairs (2 elems each)

    // --- preprocessing ---
    k_zero_int<<<nb4N, 256, 0, stream>>>(cnts, 4 * NN);
    k_scalars<<<1, 128, 0, stream>>>(t_p, tmW1, tmb1, tmW2, tmb2, g1W, scal, out_L);
    k_wprep<<<divup(6 * 16384, 256), 256, 0, stream>>>(encW1, encW2, g1W, g2W, g3W, WtS);
    k_xcast<<<2048, 256, 0, stream>>>(X, Xb, NN * 32);
    k_hist<<<nbE, 256, 0, stream>>>(dst1, cnt1, NE);
    k_hist<<<nbE, 256, 0, stream>>>(dst2, cnt2, NE);
    k_scan1<<<nbN, 256, 0, stream>>>(cnt1, rowptr1, bsum, NN);
    k_scan2<<<1, 256, 0, stream>>>(bsum, nbN);
    k_scan3<<<nbN, 256, 0, stream>>>(rowptr1, bsum, NN, NE);
    k_scan1<<<nbN, 256, 0, stream>>>(cnt2, rowptr2, bsum, NN);
    k_scan2<<<1, 256, 0, stream>>>(bsum, nbN);
    k_scan3<<<nbN, 256, 0, stream>>>(rowptr2, bsum, NN, NE);
    k_dinv<<<nbN, 256, 0, stream>>>(cnt1, dinv1, NN);
    k_dinv<<<nbN, 256, 0, stream>>>(cnt2, dinv2, NN);
    k_fill<<<nbE, 256, 0, stream>>>(src1, dst1, rowptr1, fill1, col1, NE);
    k_fill<<<nbE, 256, 0, stream>>>(src2, dst2, rowptr2, fill2, col2, NE);

    // --- encoder ---
    k_mgemm<<<nbG, 256, 0, stream>>>(Xb, W_enc1, nullptr, nullptr, nullptr, D0, NN);
    k_agg<<<nbAgg, 256, 0, stream>>>(D0, rowptr1, col1, dinv1, encb1, A1, NN, 1);
    k_agg<<<nbAgg, 256, 0, stream>>>(D0, rowptr2, col2, dinv2, encb1, A2, NN, 1);
    k_mgemm<<<nbG, 256, 0, stream>>>(A1, W_enc2, nullptr, nullptr, nullptr, D0, NN);
    k_agg<<<nbAgg, 256, 0, stream>>>(D0, rowptr1, col1, dinv1, encb2, F1, NN, 0);  // h0_v1
    k_mgemm<<<nbG, 256, 0, stream>>>(A2, W_enc2, nullptr, nullptr, nullptr, D0, NN);
    k_agg<<<nbAgg, 256, 0, stream>>>(D0, rowptr2, col2, dinv2, encb2, F2, NN, 0);  // h0_v2

    // --- h_diff out (f32) + h_t (bf16, into A1/A2 = B1/B2) ---
    k_mix<<<2048, 256, 0, stream>>>(F1, F2, noise1, noise2, scal, out_hdiff, A1, A2, total2);

    // --- denoiser layer 1 (dual GEMM + cvec) ---
    k_mgemm<<<nbG, 256, 0, stream>>>(A1, W_g1a, A2, W_g1b, scal + 2, D0, NN);
    k_agg<<<nbAgg, 256, 0, stream>>>(D0, rowptr1, col1, dinv1, g1b, V1d, NN, 1);
    k_mgemm<<<nbG, 256, 0, stream>>>(A2, W_g1a, A1, W_g1b, scal + 2, D0, NN);
    k_agg<<<nbAgg, 256, 0, stream>>>(D0, rowptr2, col2, dinv2, g1b, V2d, NN, 1);

    // --- denoiser layer 2 ---
    k_mgemm<<<nbG, 256, 0, stream>>>(V1d, W_g2, nullptr, nullptr, nullptr, D0, NN);
    k_agg<<<nbAgg, 256, 0, stream>>>(D0, rowptr1, col1, dinv1, g2b, V1d, NN, 1);
    k_mgemm<<<nbG, 256, 0, stream>>>(V2d, W_g2, nullptr, nullptr, nullptr, D0, NN);
    k_agg<<<nbAgg, 256, 0, stream>>>(D0, rowptr2, col2, dinv2, g2b, V2d, NN, 1);

    // --- denoiser layer 3 ---
    k_mgemm<<<nbG, 256, 0, stream>>>(V1d, W_g3, nullptr, nullptr, nullptr, D0, NN);
    k_agg<<<nbAgg, 256, 0, stream>>>(D0, rowptr1, col1, dinv1, g3b, F1, NN, 0);  // pred_v1
    k_mgemm<<<nbG, 256, 0, stream>>>(V2d, W_g3, nullptr, nullptr, nullptr, D0, NN);
    k_agg<<<nbAgg, 256, 0, stream>>>(D0, rowptr2, col2, dinv2, g3b, F2, NN, 0);  // pred_v2

    // --- loss ---
    k_loss<<<2048, 256, 0, stream>>>(F1, F2, noise1, noise2, out_L, total2,
                                     1.0f / (float)((size_t)NN * 128));
}

// Round 5
// 787.350 us; speedup vs baseline: 2.2360x; 1.1954x over previous
//
#include <hip/hip_runtime.h>

#define NN 50000
#define NE 600000

typedef __attribute__((ext_vector_type(8))) short short8;
typedef __attribute__((ext_vector_type(4))) float f32x4;

static inline int divup(int a, int b) { return (a + b - 1) / b; }

__device__ inline unsigned short f2bf(float f) {
    unsigned int u = __float_as_uint(f);
    unsigned int r = (u + 0x7FFFu + ((u >> 16) & 1u)) >> 16;
    return (unsigned short)r;
}
__device__ inline float bflo(unsigned int u) { return __uint_as_float(u << 16); }
__device__ inline float bfhi(unsigned int u) { return __uint_as_float(u & 0xFFFF0000u); }

// ---------------- small utility kernels ----------------

__global__ void k_zero_int(int* p, int n) {
    int i = blockIdx.x * blockDim.x + threadIdx.x;
    int stride = gridDim.x * blockDim.x;
    for (; i < n; i += stride) p[i] = 0;
}

// scalars: sqrt_ab, sqrt_1m, cvec[128] = temb @ g1_W[256:384,:], zero L out
__global__ void k_scalars(const int* __restrict__ t_p,
                          const float* __restrict__ tmW1, const float* __restrict__ tmb1,
                          const float* __restrict__ tmW2, const float* __restrict__ tmb2,
                          const float* __restrict__ g1W,
                          float* __restrict__ scal, float* __restrict__ lout) {
    __shared__ float e32[32];
    __shared__ float temb[128];
    const int tid = threadIdx.x;
    const int t = t_p[0];
    if (tid < 32) {
        float x = (float)t * tmW1[tid] + tmb1[tid];
        e32[tid] = x / (1.0f + expf(-x));  // silu
    }
    __syncthreads();
    float acc = tmb2[tid];
    for (int j = 0; j < 32; ++j) acc += e32[j] * tmW2[j * 128 + tid];
    temb[tid] = acc;
    __syncthreads();
    float cv = 0.0f;
    for (int j = 0; j < 128; ++j) cv += temb[j] * g1W[(256 + j) * 128 + tid];
    scal[2 + tid] = cv;
    if (tid == 0) {
        double ab = 1.0;
        for (int i = 0; i <= t; ++i) {
            double beta = 1e-4 + (0.02 - 1e-4) * (double)i / 99.0;
            ab *= (1.0 - beta);
        }
        scal[0] = (float)sqrt(ab);
        scal[1] = (float)sqrt(1.0 - ab);
        lout[0] = 0.0f;
    }
}

// Weight prep: 6 matrices of 128x128 f32 (row-major [k][n]) -> bf16 W^T, XOR-swizzled:
// element (n,k) stored at byte ((n<<8)|(k<<1)) ^ ((n&7)<<4) within each 32KB image.
// m: 0=encW1 1=encW2 2=g1Wa 3=g1Wb 4=g2W 5=g3W
__global__ void k_wprep(const float* __restrict__ encW1, const float* __restrict__ encW2,
                        const float* __restrict__ g1W, const float* __restrict__ g2W,
                        const float* __restrict__ g3W, unsigned short* __restrict__ WtS) {
    int i = blockIdx.x * blockDim.x + threadIdx.x;  // 0 .. 6*16384
    if (i >= 6 * 16384) return;
    int m = i >> 14;
    int r = i & 16383;
    int k = r >> 7;
    int n = r & 127;
    const float* src;
    switch (m) {
        case 0: src = encW1; break;
        case 1: src = encW2; break;
        case 2: src = g1W; break;
        case 3: src = g1W + 16384; break;
        case 4: src = g2W; break;
        default: src = g3W; break;
    }
    unsigned short v = f2bf(src[k * 128 + n]);
    unsigned int byte = (((unsigned)n << 8) | ((unsigned)k << 1)) ^ (((unsigned)n & 7u) << 4);
    WtS[(m << 14) + (byte >> 1)] = v;
}

// f32 -> bf16 cast (4 elems/thread)
__global__ void k_xcast(const float* __restrict__ in, unsigned short* __restrict__ out, int n4) {
    int i = blockIdx.x * blockDim.x + threadIdx.x;
    int stride = gridDim.x * blockDim.x;
    for (; i < n4; i += stride) {
        float4 v = ((const float4*)in)[i];
        ushort4 o;
        o.x = f2bf(v.x); o.y = f2bf(v.y); o.z = f2bf(v.z); o.w = f2bf(v.w);
        ((ushort4*)out)[i] = o;
    }
}

__global__ void k_hist(const int* __restrict__ dst, int* __restrict__ cnt, int e) {
    int i = blockIdx.x * blockDim.x + threadIdx.x;
    if (i < e) atomicAdd(&cnt[dst[i]], 1);
}

#define SCAN_B 256
__global__ void k_scan1(const int* __restrict__ cnt, int* __restrict__ exc,
                        int* __restrict__ bsum, int n) {
    __shared__ int s[SCAN_B];
    int i = blockIdx.x * SCAN_B + threadIdx.x;
    int v = (i < n) ? cnt[i] : 0;
    s[threadIdx.x] = v;
    __syncthreads();
    for (int off = 1; off < SCAN_B; off <<= 1) {
        int tv = (threadIdx.x >= off) ? s[threadIdx.x - off] : 0;
        __syncthreads();
        s[threadIdx.x] += tv;
        __syncthreads();
    }
    if (i < n) exc[i] = s[threadIdx.x] - v;
    if (threadIdx.x == SCAN_B - 1) bsum[blockIdx.x] = s[SCAN_B - 1];
}

__global__ void k_scan2(int* __restrict__ bsum, int nb) {
    __shared__ int s[SCAN_B];
    int v = (threadIdx.x < nb) ? bsum[threadIdx.x] : 0;
    s[threadIdx.x] = v;
    __syncthreads();
    for (int off = 1; off < SCAN_B; off <<= 1) {
        int tv = (threadIdx.x >= off) ? s[threadIdx.x - off] : 0;
        __syncthreads();
        s[threadIdx.x] += tv;
        __syncthreads();
    }
    if (threadIdx.x < nb) bsum[threadIdx.x] = s[threadIdx.x] - v;
}

__global__ void k_scan3(int* __restrict__ exc, const int* __restrict__ bsum, int n, int total) {
    int i = blockIdx.x * SCAN_B + threadIdx.x;
    if (i < n) exc[i] += bsum[blockIdx.x];
    if (i == 0) exc[n] = total;
}

__global__ void k_fill(const int* __restrict__ src, const int* __restrict__ dst,
                       const int* __restrict__ rowptr, int* __restrict__ fill,
                       int* __restrict__ colA, int e) {
    int i = blockIdx.x * blockDim.x + threadIdx.x;
    if (i < e) {
        int d = dst[i];
        int p = atomicAdd(&fill[d], 1);
        colA[rowptr[d] + p] = src[i];
    }
}

__global__ void k_dinv(const int* __restrict__ cnt, float* __restrict__ dinv, int n) {
    int i = blockIdx.x * blockDim.x + threadIdx.x;
    if (i < n) dinv[i] = rsqrtf((float)cnt[i] + 1.0f);  // +1 = self loop
}

// ---------------- MFMA GEMM: out(bf16) = A@Wa (+ B@Wb) (+ cvec) ----------------
// A,B: bf16 [nrows][128] row-major. Wa,Wb: pre-swizzled bf16 W^T 32KB images.
// Block: 64 rows, 4 waves; wave = 16 rows x 128 cols; 16x16x32 MFMA.
__global__ __launch_bounds__(256) void k_mgemm(
    const unsigned short* __restrict__ A, const unsigned short* __restrict__ Wa,
    const unsigned short* __restrict__ B, const unsigned short* __restrict__ Wb,
    const float* __restrict__ cvec, unsigned short* __restrict__ out, int nrows) {
    __shared__ unsigned short sW[16384];  // 32KB swizzled W^T
    const int tid = threadIdx.x;
    const int wv = tid >> 6;
    const int l = tid & 63;
    const int lrow = l & 15;   // A-row / C-col within tile
    const int lk = l >> 4;     // 0..3: K-subgroup / C-row-group
    const int r0 = blockIdx.x * 64 + wv * 16;

    f32x4 acc[8];
#pragma unroll
    for (int ct = 0; ct < 8; ++ct) acc[ct] = (f32x4){0.f, 0.f, 0.f, 0.f};

    const unsigned short* Aptr[2] = {A, B};
    const unsigned short* Wptr[2] = {Wa, Wb};
    const int np = (B != nullptr) ? 2 : 1;

    int arow = r0 + lrow;
    if (arow >= nrows) arow = nrows - 1;

    for (int p = 0; p < np; ++p) {
        __syncthreads();  // protect sW from previous pass readers
        {
            const uint4* s = (const uint4*)Wptr[p];
            uint4* d = (uint4*)sW;
#pragma unroll
            for (int j = 0; j < 8; ++j) d[tid + j * 256] = s[tid + j * 256];
        }
        __syncthreads();
        const unsigned short* abase = Aptr[p] + (size_t)arow * 128 + lk * 8;
#pragma unroll
        for (int ks = 0; ks < 4; ++ks) {
            short8 af = *(const short8*)(abase + ks * 32);
            const int kb2 = (lk * 8 + ks * 32) << 1;  // byte offset of k-base
#pragma unroll
            for (int ct = 0; ct < 8; ++ct) {
                int n = ct * 16 + lrow;
                int byteoff = ((n << 8) + kb2) ^ ((l & 7) << 4);
                short8 bf = *(const short8*)((const char*)sW + byteoff);
                acc[ct] = __builtin_amdgcn_mfma_f32_16x16x32_bf16(af, bf, acc[ct], 0, 0, 0);
            }
        }
    }
    // epilogue: C[row = r0 + lk*4 + reg][col = ct*16 + lrow]
#pragma unroll
    for (int ct = 0; ct < 8; ++ct) {
        float cv = cvec ? cvec[ct * 16 + lrow] : 0.0f;
#pragma unroll
        for (int rg = 0; rg < 4; ++rg) {
            int row = r0 + lk * 4 + rg;
            if (row < nrows) out[(size_t)row * 128 + ct * 16 + lrow] = f2bf(acc[ct][rg] + cv);
        }
    }
}

// ---------------- GCN aggregation (bf16 in, bf16 out) ----------------
// out[d] = relu?( dinv[d]*(dinv[d]*h[d] + sum_s dinv[s]*h[s]) + b )
// One wave per dst row; quarter-wave (16 lanes x 16B) per gathered row ->
// 4 edge-rows in flight per wave. Cross-group combine via shfl_xor.
__global__ __launch_bounds__(256) void k_agg(
    const unsigned short* __restrict__ h, const int* __restrict__ rowptr,
    const int* __restrict__ colA, const float* __restrict__ dinv,
    const float* __restrict__ bias, unsigned short* __restrict__ out, int n, int do_relu) {
    const int d = (blockIdx.x * blockDim.x + threadIdx.x) >> 6;
    const int l = threadIdx.x & 63;
    if (d >= n) return;
    const int lg = l >> 4;   // quarter-wave group 0..3
    const int ll = l & 15;   // lane within group; owns features ll*8..ll*8+7
    const float di = dinv[d];

    float acc[8];
#pragma unroll
    for (int k = 0; k < 8; ++k) acc[k] = 0.0f;

    const int e0 = rowptr[d];
    const int e1 = rowptr[d + 1];
    for (int base = e0; base < e1; base += 64) {
        int cnt = min(64, e1 - base);
        int cs = 0;
        float ws = 0.0f;
        if (base + l < e1) {
            cs = colA[base + l];
            ws = dinv[cs];
        }
        for (int j4 = 0; j4 < cnt; j4 += 4) {
            int idx = j4 + lg;                    // <=63; lanes>=cnt hold ws=0
            int s = __shfl(cs, idx);
            float w = __shfl(ws, idx);
            uint4 u = *((const uint4*)(h + (size_t)s * 128) + ll);
            acc[0] += w * bflo(u.x);
            acc[1] += w * bfhi(u.x);
            acc[2] += w * bflo(u.y);
            acc[3] += w * bfhi(u.y);
            acc[4] += w * bflo(u.z);
            acc[5] += w * bfhi(u.z);
            acc[6] += w * bflo(u.w);
            acc[7] += w * bfhi(u.w);
        }
    }
    // combine the 4 groups (same features live at same ll in each group)
#pragma unroll
    for (int k = 0; k < 8; ++k) {
        acc[k] += __shfl_xor(acc[k], 16);
        acc[k] += __shfl_xor(acc[k], 32);
    }
    if (lg == 0) {
        uint4 su = *((const uint4*)(h + (size_t)d * 128) + ll);
        float4 b0 = ((const float4*)bias)[ll * 2];
        float4 b1 = ((const float4*)bias)[ll * 2 + 1];
        float sf[8] = {bflo(su.x), bfhi(su.x), bflo(su.y), bfhi(su.y),
                       bflo(su.z), bfhi(su.z), bflo(su.w), bfhi(su.w)};
        float bb[8] = {b0.x, b0.y, b0.z, b0.w, b1.x, b1.y, b1.z, b1.w};
        unsigned short o[8];
#pragma unroll
        for (int k = 0; k < 8; ++k) {
            float v = di * (acc[k] + di * sf[k]) + bb[k];
            if (do_relu) v = fmaxf(v, 0.0f);
            o[k] = f2bf(v);
        }
        uint4 ov;
        ov.x = (unsigned int)o[0] | ((unsigned int)o[1] << 16);
        ov.y = (unsigned int)o[2] | ((unsigned int)o[3] << 16);
        ov.z = (unsigned int)o[4] | ((unsigned int)o[5] << 16);
        ov.w = (unsigned int)o[6] | ((unsigned int)o[7] << 16);
        *((uint4*)(out + (size_t)d * 128) + ll) = ov;
    }
}

// ---------------- h_diff (f32 out) + h_t (bf16) ----------------
__global__ void k_mix(const unsigned short* __restrict__ F1, const unsigned short* __restrict__ F2,
                      const float* __restrict__ n1, const float* __restrict__ n2,
                      const float* __restrict__ scal, float* __restrict__ hdiff,
                      unsigned short* __restrict__ B1, unsigned short* __restrict__ B2, int total2) {
    const float sa = scal[0];
    const float sm = scal[1];
    int i = blockIdx.x * blockDim.x + threadIdx.x;
    const int stride = gridDim.x * blockDim.x;
    for (; i < total2; i += stride) {
        unsigned int u1 = ((const unsigned int*)F1)[i];
        unsigned int u2 = ((const unsigned int*)F2)[i];
        float a0 = bflo(u1), a1 = bfhi(u1);
        float b0 = bflo(u2), b1 = bfhi(u2);
        float2 x = ((const float2*)n1)[i];
        float2 y = ((const float2*)n2)[i];
        float2 hd;
        hd.x = 0.5f * (a0 + b0);
        hd.y = 0.5f * (a1 + b1);
        ((float2*)hdiff)[i] = hd;
        float h1x = sa * a0 + sm * x.x, h1y = sa * a1 + sm * x.y;
        float h2x = sa * b0 + sm * y.x, h2y = sa * b1 + sm * y.y;
        ((unsigned int*)B1)[i] = (unsigned int)f2bf(h1x) | ((unsigned int)f2bf(h1y) << 16);
        ((unsigned int*)B2)[i] = (unsigned int)f2bf(h2x) | ((unsigned int)f2bf(h2y) << 16);
    }
}

// ---------------- L_diff ----------------
__global__ void k_loss(const unsigned short* __restrict__ P1, const unsigned short* __restrict__ P2,
                       const float* __restrict__ n1, const float* __restrict__ n2,
                       float* __restrict__ outs, int total2, float inv_total) {
    float s = 0.0f;
    int i = blockIdx.x * blockDim.x + threadIdx.x;
    const int stride = gridDim.x * blockDim.x;
    for (; i < total2; i += stride) {
        unsigned int u1 = ((const unsigned int*)P1)[i];
        unsigned int u2 = ((const unsigned int*)P2)[i];
        float2 x = ((const float2*)n1)[i];
        float2 y = ((const float2*)n2)[i];
        float d0 = bflo(u1) - x.x, d1 = bfhi(u1) - x.y;
        float d2 = bflo(u2) - y.x, d3 = bfhi(u2) - y.y;
        s += d0 * d0 + d1 * d1 + d2 * d2 + d3 * d3;
    }
    __shared__ float red[4];
    for (int off = 32; off > 0; off >>= 1) s += __shfl_down(s, off, 64);
    const int lane = threadIdx.x & 63;
    const int wid = threadIdx.x >> 6;
    if (lane == 0) red[wid] = s;
    __syncthreads();
    if (threadIdx.x == 0) {
        float t = red[0] + red[1] + red[2] + red[3];
        atomicAdd(outs, t * inv_total);
    }
}

// ---------------- host ----------------
extern "C" void kernel_launch(void* const* d_in, const int* in_sizes, int n_in,
                              void* d_out, int out_size, void* d_ws, size_t ws_size,
                              hipStream_t stream) {
    const float* X      = (const float*)d_in[0];
    const int*   ei1    = (const int*)d_in[1];
    const int*   ei2    = (const int*)d_in[2];
    const int*   t_p    = (const int*)d_in[3];
    const float* noise1 = (const float*)d_in[4];
    const float* noise2 = (const float*)d_in[5];
    const float* encW1  = (const float*)d_in[6];
    const float* encb1  = (const float*)d_in[7];
    const float* encW2  = (const float*)d_in[8];
    const float* encb2  = (const float*)d_in[9];
    const float* tmW1   = (const float*)d_in[10];
    const float* tmb1   = (const float*)d_in[11];
    const float* tmW2   = (const float*)d_in[12];
    const float* tmb2   = (const float*)d_in[13];
    const float* g1W    = (const float*)d_in[14];
    const float* g1b    = (const float*)d_in[15];
    const float* g2W    = (const float*)d_in[16];
    const float* g2b    = (const float*)d_in[17];
    const float* g3W    = (const float*)d_in[18];
    const float* g3b    = (const float*)d_in[19];

    float* out_hdiff = (float*)d_out;
    float* out_L     = (float*)d_out + (size_t)NN * 128;

    char* p = (char*)d_ws;
    auto alloc = [&](size_t bytes) -> void* {
        void* r = (void*)p;
        p += (bytes + 255) & ~(size_t)255;
        return r;
    };
    int* cnts = (int*)alloc((size_t)4 * NN * sizeof(int));
    int *cnt1 = cnts, *cnt2 = cnts + NN, *fill1 = cnts + 2 * NN, *fill2 = cnts + 3 * NN;
    int* rowptr1 = (int*)alloc((NN + 1) * sizeof(int));
    int* rowptr2 = (int*)alloc((NN + 1) * sizeof(int));
    int* bsum    = (int*)alloc(256 * sizeof(int));
    int* col1    = (int*)alloc((size_t)NE * sizeof(int));
    int* col2    = (int*)alloc((size_t)NE * sizeof(int));
    float* dinv1 = (float*)alloc(NN * sizeof(float));
    float* dinv2 = (float*)alloc(NN * sizeof(float));
    float* scal  = (float*)alloc(256 * sizeof(float));  // [0]=sa [1]=sm [2..129]=cvec
    unsigned short* WtS = (unsigned short*)alloc((size_t)6 * 16384 * sizeof(unsigned short));
    const size_t FB = (size_t)NN * 128;
    unsigned short* Xb = (unsigned short*)alloc(FB * 2);  // also V1d (denoiser v1 act)
    unsigned short* A1 = (unsigned short*)alloc(FB * 2);  // enc act v1, then B1 (h_t_v1)
    unsigned short* A2 = (unsigned short*)alloc(FB * 2);  // enc act v2, then B2 (h_t_v2)
    unsigned short* D0 = (unsigned short*)alloc(FB * 2);  // GEMM->agg scratch
    unsigned short* F1 = (unsigned short*)alloc(FB * 2);  // h0_v1, then pred_v1
    unsigned short* F2 = (unsigned short*)alloc(FB * 2);  // h0_v2, then V2d, then pred_v2
    unsigned short* V1d = Xb;
    unsigned short* V2d = F2;

    const unsigned short* W_enc1 = WtS;
    const unsigned short* W_enc2 = WtS + 1 * 16384;
    const unsigned short* W_g1a  = WtS + 2 * 16384;
    const unsigned short* W_g1b  = WtS + 3 * 16384;
    const unsigned short* W_g2   = WtS + 4 * 16384;
    const unsigned short* W_g3   = WtS + 5 * 16384;

    const int* src1 = ei1;
    const int* dst1 = ei1 + NE;
    const int* src2 = ei2;
    const int* dst2 = ei2 + NE;

    const int nbN   = divup(NN, 256);
    const int nbE   = divup(NE, 256);
    const int nb4N  = divup(4 * NN, 256);
    const int nbG   = divup(NN, 64);   // 782
    const int nbAgg = divup(NN, 4);    // 12500
    const int total2 = NN * 64;        // uint-pairs (2 elems each)

    // --- preprocessing ---
    k_zero_int<<<nb4N, 256, 0, stream>>>(cnts, 4 * NN);
    k_scalars<<<1, 128, 0, stream>>>(t_p, tmW1, tmb1, tmW2, tmb2, g1W, scal, out_L);
    k_wprep<<<divup(6 * 16384, 256), 256, 0, stream>>>(encW1, encW2, g1W, g2W, g3W, WtS);
    k_xcast<<<2048, 256, 0, stream>>>(X, Xb, NN * 32);
    k_hist<<<nbE, 256, 0, stream>>>(dst1, cnt1, NE);
    k_hist<<<nbE, 256, 0, stream>>>(dst2, cnt2, NE);
    k_scan1<<<nbN, 256, 0, stream>>>(cnt1, rowptr1, bsum, NN);
    k_scan2<<<1, 256, 0, stream>>>(bsum, nbN);
    k_scan3<<<nbN, 256, 0, stream>>>(rowptr1, bsum, NN, NE);
    k_scan1<<<nbN, 256, 0, stream>>>(cnt2, rowptr2, bsum, NN);
    k_scan2<<<1, 256, 0, stream>>>(bsum, nbN);
    k_scan3<<<nbN, 256, 0, stream>>>(rowptr2, bsum, NN, NE);
    k_dinv<<<nbN, 256, 0, stream>>>(cnt1, dinv1, NN);
    k_dinv<<<nbN, 256, 0, stream>>>(cnt2, dinv2, NN);
    k_fill<<<nbE, 256, 0, stream>>>(src1, dst1, rowptr1, fill1, col1, NE);
    k_fill<<<nbE, 256, 0, stream>>>(src2, dst2, rowptr2, fill2, col2, NE);

    // --- encoder ---
    k_mgemm<<<nbG, 256, 0, stream>>>(Xb, W_enc1, nullptr, nullptr, nullptr, D0, NN);
    k_agg<<<nbAgg, 256, 0, stream>>>(D0, rowptr1, col1, dinv1, encb1, A1, NN, 1);
    k_agg<<<nbAgg, 256, 0, stream>>>(D0, rowptr2, col2, dinv2, encb1, A2, NN, 1);
    k_mgemm<<<nbG, 256, 0, stream>>>(A1, W_enc2, nullptr, nullptr, nullptr, D0, NN);
    k_agg<<<nbAgg, 256, 0, stream>>>(D0, rowptr1, col1, dinv1, encb2, F1, NN, 0);  // h0_v1
    k_mgemm<<<nbG, 256, 0, stream>>>(A2, W_enc2, nullptr, nullptr, nullptr, D0, NN);
    k_agg<<<nbAgg, 256, 0, stream>>>(D0, rowptr2, col2, dinv2, encb2, F2, NN, 0);  // h0_v2

    // --- h_diff out (f32) + h_t (bf16, into A1/A2 = B1/B2) ---
    k_mix<<<2048, 256, 0, stream>>>(F1, F2, noise1, noise2, scal, out_hdiff, A1, A2, total2);

    // --- denoiser layer 1 (dual GEMM + cvec) ---
    k_mgemm<<<nbG, 256, 0, stream>>>(A1, W_g1a, A2, W_g1b, scal + 2, D0, NN);
    k_agg<<<nbAgg, 256, 0, stream>>>(D0, rowptr1, col1, dinv1, g1b, V1d, NN, 1);
    k_mgemm<<<nbG, 256, 0, stream>>>(A2, W_g1a, A1, W_g1b, scal + 2, D0, NN);
    k_agg<<<nbAgg, 256, 0, stream>>>(D0, rowptr2, col2, dinv2, g1b, V2d, NN, 1);

    // --- denoiser layer 2 ---
    k_mgemm<<<nbG, 256, 0, stream>>>(V1d, W_g2, nullptr, nullptr, nullptr, D0, NN);
    k_agg<<<nbAgg, 256, 0, stream>>>(D0, rowptr1, col1, dinv1, g2b, V1d, NN, 1);
    k_mgemm<<<nbG, 256, 0, stream>>>(V2d, W_g2, nullptr, nullptr, nullptr, D0, NN);
    k_agg<<<nbAgg, 256, 0, stream>>>(D0, rowptr2, col2, dinv2, g2b, V2d, NN, 1);

    // --- denoiser layer 3 ---
    k_mgemm<<<nbG, 256, 0, stream>>>(V1d, W_g3, nullptr, nullptr, nullptr, D0, NN);
    k_agg<<<nbAgg, 256, 0, stream>>>(D0, rowptr1, col1, dinv1, g3b, F1, NN, 0);  // pred_v1
    k_mgemm<<<nbG, 256, 0, stream>>>(V2d, W_g3, nullptr, nullptr, nullptr, D0, NN);
    k_agg<<<nbAgg, 256, 0, stream>>>(D0, rowptr2, col2, dinv2, g3b, F2, NN, 0);  // pred_v2

    // --- loss ---
    k_loss<<<2048, 256, 0, stream>>>(F1, F2, noise1, noise2, out_L, total2,
                                     1.0f / (float)((size_t)NN * 128));
}